// Round 14
// baseline (118.524 us; speedup 1.0000x reference)
//
#include <hip/hip_runtime.h>

// Fused tanh-RNN (T=64, I=64, H=100) + tanh + linear (C=40), B=16384.
// TRANSPOSED formulation, interleaved-phi f16 weights (pkrtz-packable).
//
// Round-14: SOFTWARE-SMT. Occupancy is structurally capped at 1 wave/SIMD
// (1024 tiles / 1024 SIMDs), so the per-step stall tail (MFMA result ->
// tanh -> pack -> next step) can only be filled from INSIDE the wave:
// one wave now owns TWO independent 16-row tiles (A,B), phases interleaved
//   [dsA+dsB reads | A 42 MFMA | B 42 MFMA | A tanh/pack | B tanh/pack]
// so each tile's latency tail is covered by the other tile's work.
// Weights shared (196 VGPR amortized over 2 tiles). LDS = 64KB exactly:
// per tile 2 slab buffers x 16 rows x 1024B (4 steps), no pad; bank
// conflicts fixed by XOR swizzle bits5-6 ((c&3)<<5) applied via
// pre-swizzled global DMA source (LDS dest stays linear).

typedef _Float16 half8 __attribute__((ext_vector_type(8)));
typedef float float4_t __attribute__((ext_vector_type(4)));
typedef unsigned int uint4_t __attribute__((ext_vector_type(4)));

#define SLAB_BYTES 16384               // 16 rows x 1024 B (4 steps)
#define TILE_LDS   (2 * SLAB_BYTES)    // double-buffered per tile
#define GLOAD16(gp, lp)                                                   \
  __builtin_amdgcn_global_load_lds(                                       \
      (const __attribute__((address_space(1))) void*)(gp),                \
      (__attribute__((address_space(3))) void*)(lp), 16, 0, 0)

__device__ __forceinline__ float tanh_fast(float x) {
  float e = __builtin_amdgcn_exp2f(x * 2.8853900817779268f);
  return 1.0f - 2.0f * __builtin_amdgcn_rcpf(e + 1.0f);
}
__device__ __forceinline__ unsigned int pk2(float lo, float hi) {
  return __builtin_bit_cast(unsigned int, __builtin_amdgcn_cvt_pkrtz(lo, hi));
}
__device__ __forceinline__ half8 pack4(unsigned int a, unsigned int b,
                                       unsigned int c, unsigned int d) {
  uint4_t u = {a, b, c, d};
  return __builtin_bit_cast(half8, u);
}

// One slab: row j's bytes [slab*1024, +1024) -> buf + j*1024 (linear dest).
// Global source pre-swizzled: float idx (lane*4) ^ ((j&3)<<3)  == byte
// (lane*16) ^ ((j&3)<<5), so LDS pos p holds global byte p ^ ((j&3)<<5).
__device__ __forceinline__ void issue_slab(const float* srcT, int slab,
                                           char* buf, int lane) {
  #pragma unroll
  for (int j = 0; j < 16; ++j) {
    int loff = (lane * 4) ^ ((j & 3) << 3);
    GLOAD16(srcT + (size_t)j * 4096 + slab * 256 + loff, buf + j * 1024);
  }
}

__global__ __launch_bounds__(64, 1) void rnn_fused(
    const float* __restrict__ x, const float* __restrict__ W_ih,
    const float* __restrict__ W_hh, const float* __restrict__ b_ih,
    const float* __restrict__ b_hh, const float* __restrict__ fc_W,
    const float* __restrict__ fc_b, float* __restrict__ out, int B)
{
  __shared__ char xlds[2 * TILE_LDS];   // 65536 B
  const int lane = threadIdx.x & 63;
  const int g = lane >> 4;
  const int c = lane & 15;
  const int rowbase = blockIdx.x * 32;  // tile A: +0..15, tile B: +16..31

  const float* srcA = x + (size_t)rowbase * 4096;
  const float* srcB = srcA + (size_t)16 * 4096;
  char* ldsA = xlds;
  char* ldsB = xlds + TILE_LDS;

  // prologue DMA: A0,B0 first, then A1,B1 (so vmcnt(32) => slab0 done)
  issue_slab(srcA, 0, ldsA, lane);
  issue_slab(srcB, 0, ldsB, lane);
  issue_slab(srcA, 1, ldsA + SLAB_BYTES, lane);
  issue_slab(srcB, 1, ldsB + SLAB_BYTES, lane);

  // ---- shared weights (interleaved phi placement), register-resident
  half8 wih[2][7];
  half8 whh[4][7];
  float4_t bias[7];
  #pragma unroll
  for (int nt = 0; nt < 7; ++nt) {
    int nb = nt * 16 + 4 * g;
    float4_t bi = {0.f, 0.f, 0.f, 0.f};
    if (nb + 3 < 100) {
      float4_t a = *(const float4_t*)(b_ih + nb);
      float4_t b = *(const float4_t*)(b_hh + nb);
      bi = a + b;
    }
    bias[nt] = bi;

    int nrow = nt * 16 + c;
    bool rv = (nrow < 100);
    #pragma unroll
    for (int kb = 0; kb < 2; ++kb) {
      float4_t f0 = {0.f,0.f,0.f,0.f}, f1 = {0.f,0.f,0.f,0.f};
      if (rv) {
        const float* p = W_ih + nrow * 64 + kb * 32 + g * 8;
        f0 = *(const float4_t*)p;
        f1 = *(const float4_t*)(p + 4);
      }
      half8 h;
      #pragma unroll
      for (int j = 0; j < 4; ++j) { h[2*j] = (_Float16)f0[j]; h[2*j+1] = (_Float16)f1[j]; }
      wih[kb][nt] = h;
    }
    #pragma unroll
    for (int kb = 0; kb < 4; ++kb) {
      int clo = kb * 32 + 4 * g;
      int chi = clo + 16;
      float4_t f0 = {0.f,0.f,0.f,0.f}, f1 = {0.f,0.f,0.f,0.f};
      if (rv && clo + 3 < 100) f0 = *(const float4_t*)(W_hh + nrow * 100 + clo);
      if (rv && chi + 3 < 100) f1 = *(const float4_t*)(W_hh + nrow * 100 + chi);
      half8 h;
      #pragma unroll
      for (int j = 0; j < 4; ++j) { h[2*j] = (_Float16)f0[j]; h[2*j+1] = (_Float16)f1[j]; }
      whh[kb][nt] = h;
    }
  }

  // reader base: c*1024 + ((g*32) ^ ((c&3)<<5)); adds (t4*256, 16/128/144,
  // buffer offset) live in disjoint bits -> XOR stays valid.
  const unsigned lb =
      (unsigned)(uintptr_t)(__attribute__((address_space(3))) char*)xlds;
  const unsigned baseA = lb + (unsigned)(c * 1024 + ((g * 32) ^ ((c & 3) << 5)));
  const unsigned baseB = baseA + TILE_LDS;

  float4_t accA[7], accB[7];
  half8 hfA[4], hfB[4];
  #pragma unroll
  for (int kb = 0; kb < 4; ++kb) {
    hfA[kb] = (half8)(_Float16)0.0f;
    hfB[kb] = (half8)(_Float16)0.0f;
  }

  for (int grp = 0; grp < 16; ++grp) {
    // slab grp complete for both tiles once only the 32 newer DMAs remain
    asm volatile("s_waitcnt vmcnt(32)" ::: "memory");
    const unsigned offg = (unsigned)((grp & 1) * SLAB_BYTES);

    #pragma unroll
    for (int t4 = 0; t4 < 4; ++t4) {
      unsigned aA = baseA + offg + (unsigned)(t4 * 256);
      unsigned aB = baseB + offg + (unsigned)(t4 * 256);
      float4_t sa0, sa1, sa2, sa3, sb0, sb1, sb2, sb3;
      asm volatile(
          "ds_read_b128 %0, %4 offset:0\n\t"
          "ds_read_b128 %1, %4 offset:16\n\t"
          "ds_read_b128 %2, %4 offset:128\n\t"
          "ds_read_b128 %3, %4 offset:144"
          : "=&v"(sa0), "=&v"(sa1), "=&v"(sa2), "=&v"(sa3)
          : "v"(aA) : "memory");
      asm volatile(
          "ds_read_b128 %0, %4 offset:0\n\t"
          "ds_read_b128 %1, %4 offset:16\n\t"
          "ds_read_b128 %2, %4 offset:128\n\t"
          "ds_read_b128 %3, %4 offset:144"
          : "=&v"(sb0), "=&v"(sb1), "=&v"(sb2), "=&v"(sb3)
          : "v"(aB) : "memory");

      // ---- tile A: recurrence (register-fed)
      #pragma unroll
      for (int nt = 0; nt < 7; ++nt)
        accA[nt] = __builtin_amdgcn_mfma_f32_16x16x32_f16(whh[0][nt], hfA[0], bias[nt], 0, 0, 0);
      #pragma unroll
      for (int kb = 1; kb < 4; ++kb)
        #pragma unroll
        for (int nt = 0; nt < 7; ++nt)
          accA[nt] = __builtin_amdgcn_mfma_f32_16x16x32_f16(whh[kb][nt], hfA[kb], accA[nt], 0, 0, 0);

      // A's x data (first 4 of the 8 ds_reads; DS completes in order)
      asm volatile("s_waitcnt lgkmcnt(4)"
                   : "+v"(sa0), "+v"(sa1), "+v"(sa2), "+v"(sa3) :: "memory");
      __builtin_amdgcn_sched_barrier(0);
      half8 xa0 = pack4(pk2(sa0[0], sa1[0]), pk2(sa0[1], sa1[1]),
                        pk2(sa0[2], sa1[2]), pk2(sa0[3], sa1[3]));
      half8 xa1 = pack4(pk2(sa2[0], sa3[0]), pk2(sa2[1], sa3[1]),
                        pk2(sa2[2], sa3[2]), pk2(sa2[3], sa3[3]));
      #pragma unroll
      for (int nt = 0; nt < 7; ++nt) {
        accA[nt] = __builtin_amdgcn_mfma_f32_16x16x32_f16(wih[0][nt], xa0, accA[nt], 0, 0, 0);
        accA[nt] = __builtin_amdgcn_mfma_f32_16x16x32_f16(wih[1][nt], xa1, accA[nt], 0, 0, 0);
      }

      // ---- tile B: recurrence (fills A's MFMA latency tail)
      #pragma unroll
      for (int nt = 0; nt < 7; ++nt)
        accB[nt] = __builtin_amdgcn_mfma_f32_16x16x32_f16(whh[0][nt], hfB[0], bias[nt], 0, 0, 0);
      #pragma unroll
      for (int kb = 1; kb < 4; ++kb)
        #pragma unroll
        for (int nt = 0; nt < 7; ++nt)
          accB[nt] = __builtin_amdgcn_mfma_f32_16x16x32_f16(whh[kb][nt], hfB[kb], accB[nt], 0, 0, 0);

      asm volatile("s_waitcnt lgkmcnt(0)"
                   : "+v"(sb0), "+v"(sb1), "+v"(sb2), "+v"(sb3) :: "memory");
      __builtin_amdgcn_sched_barrier(0);
      half8 xb0 = pack4(pk2(sb0[0], sb1[0]), pk2(sb0[1], sb1[1]),
                        pk2(sb0[2], sb1[2]), pk2(sb0[3], sb1[3]));
      half8 xb1 = pack4(pk2(sb2[0], sb3[0]), pk2(sb2[1], sb3[1]),
                        pk2(sb2[2], sb3[2]), pk2(sb2[3], sb3[3]));
      #pragma unroll
      for (int nt = 0; nt < 7; ++nt) {
        accB[nt] = __builtin_amdgcn_mfma_f32_16x16x32_f16(wih[0][nt], xb0, accB[nt], 0, 0, 0);
        accB[nt] = __builtin_amdgcn_mfma_f32_16x16x32_f16(wih[1][nt], xb1, accB[nt], 0, 0, 0);
      }

      // ---- tile A: tanh + pack (B's MFMAs still in flight behind us)
      #pragma unroll
      for (int nt = 0; nt < 7; ++nt)
        #pragma unroll
        for (int v = 0; v < 4; ++v)
          accA[nt][v] = tanh_fast(accA[nt][v]);
      #pragma unroll
      for (int kb = 0; kb < 3; ++kb)
        hfA[kb] = pack4(pk2(accA[2*kb][0], accA[2*kb+1][0]),
                        pk2(accA[2*kb][1], accA[2*kb+1][1]),
                        pk2(accA[2*kb][2], accA[2*kb+1][2]),
                        pk2(accA[2*kb][3], accA[2*kb+1][3]));
      hfA[3] = pack4(pk2(accA[6][0], 0.0f), pk2(accA[6][1], 0.0f),
                     pk2(accA[6][2], 0.0f), pk2(accA[6][3], 0.0f));

      // ---- tile B: tanh + pack
      #pragma unroll
      for (int nt = 0; nt < 7; ++nt)
        #pragma unroll
        for (int v = 0; v < 4; ++v)
          accB[nt][v] = tanh_fast(accB[nt][v]);
      #pragma unroll
      for (int kb = 0; kb < 3; ++kb)
        hfB[kb] = pack4(pk2(accB[2*kb][0], accB[2*kb+1][0]),
                        pk2(accB[2*kb][1], accB[2*kb+1][1]),
                        pk2(accB[2*kb][2], accB[2*kb+1][2]),
                        pk2(accB[2*kb][3], accB[2*kb+1][3]));
      hfB[3] = pack4(pk2(accB[6][0], 0.0f), pk2(accB[6][1], 0.0f),
                     pk2(accB[6][2], 0.0f), pk2(accB[6][3], 0.0f));
    }

    // refill the buffers just finished (clamped tail keeps cadence)
    int sl = grp + 2; if (sl > 15) sl = 15;
    issue_slab(srcA, sl, ldsA + (sl & 1) * SLAB_BYTES, lane);
    issue_slab(srcB, sl, ldsB + (sl & 1) * SLAB_BYTES, lane);
  }

  // ---- epilogue: z = tanh(h_64); out = z @ fc_W^T + fc_b (phi-permuted)
  half8 zfA[4], zfB[4];
  #pragma unroll
  for (int nt = 0; nt < 7; ++nt)
    #pragma unroll
    for (int v = 0; v < 4; ++v) {
      accA[nt][v] = tanh_fast(accA[nt][v]);
      accB[nt][v] = tanh_fast(accB[nt][v]);
    }
  #pragma unroll
  for (int kb = 0; kb < 3; ++kb) {
    zfA[kb] = pack4(pk2(accA[2*kb][0], accA[2*kb+1][0]),
                    pk2(accA[2*kb][1], accA[2*kb+1][1]),
                    pk2(accA[2*kb][2], accA[2*kb+1][2]),
                    pk2(accA[2*kb][3], accA[2*kb+1][3]));
    zfB[kb] = pack4(pk2(accB[2*kb][0], accB[2*kb+1][0]),
                    pk2(accB[2*kb][1], accB[2*kb+1][1]),
                    pk2(accB[2*kb][2], accB[2*kb+1][2]),
                    pk2(accB[2*kb][3], accB[2*kb+1][3]));
  }
  zfA[3] = pack4(pk2(accA[6][0], 0.0f), pk2(accA[6][1], 0.0f),
                 pk2(accA[6][2], 0.0f), pk2(accA[6][3], 0.0f));
  zfB[3] = pack4(pk2(accB[6][0], 0.0f), pk2(accB[6][1], 0.0f),
                 pk2(accB[6][2], 0.0f), pk2(accB[6][3], 0.0f));

  half8 wfc[4][3];
  float4_t bfc[3];
  #pragma unroll
  for (int nt = 0; nt < 3; ++nt) {
    int nb = nt * 16 + 4 * g;
    float4_t bi = {0.f,0.f,0.f,0.f};
    if (nb + 3 < 40) bi = *(const float4_t*)(fc_b + nb);
    bfc[nt] = bi;

    int nrow = nt * 16 + c;
    bool rv = (nrow < 40);
    #pragma unroll
    for (int kb = 0; kb < 4; ++kb) {
      int clo = kb * 32 + 4 * g;
      int chi = clo + 16;
      float4_t f0 = {0.f,0.f,0.f,0.f}, f1 = {0.f,0.f,0.f,0.f};
      if (rv && clo + 3 < 100) f0 = *(const float4_t*)(fc_W + nrow * 100 + clo);
      if (rv && chi + 3 < 100) f1 = *(const float4_t*)(fc_W + nrow * 100 + chi);
      half8 h;
      #pragma unroll
      for (int j = 0; j < 4; ++j) { h[2*j] = (_Float16)f0[j]; h[2*j+1] = (_Float16)f1[j]; }
      wfc[kb][nt] = h;
    }
  }

  float4_t oaccA[3], oaccB[3];
  #pragma unroll
  for (int nt = 0; nt < 3; ++nt) { oaccA[nt] = bfc[nt]; oaccB[nt] = bfc[nt]; }
  #pragma unroll
  for (int kb = 0; kb < 4; ++kb)
    #pragma unroll
    for (int nt = 0; nt < 3; ++nt) {
      oaccA[nt] = __builtin_amdgcn_mfma_f32_16x16x32_f16(wfc[kb][nt], zfA[kb], oaccA[nt], 0, 0, 0);
      oaccB[nt] = __builtin_amdgcn_mfma_f32_16x16x32_f16(wfc[kb][nt], zfB[kb], oaccB[nt], 0, 0, 0);
    }

  #pragma unroll
  for (int nt = 0; nt < 3; ++nt)
    #pragma unroll
    for (int v = 0; v < 4; ++v) {
      int n = nt * 16 + 4 * g + v;
      if (n < 40) {
        out[(size_t)(rowbase + c) * 40 + n] = oaccA[nt][v];
        out[(size_t)(rowbase + 16 + c) * 40 + n] = oaccB[nt][v];
      }
    }
}

extern "C" void kernel_launch(void* const* d_in, const int* in_sizes, int n_in,
                              void* d_out, int out_size, void* d_ws, size_t ws_size,
                              hipStream_t stream) {
  const float* x    = (const float*)d_in[0];
  const float* W_ih = (const float*)d_in[1];
  const float* W_hh = (const float*)d_in[2];
  const float* b_ih = (const float*)d_in[3];
  const float* b_hh = (const float*)d_in[4];
  const float* fc_W = (const float*)d_in[5];
  const float* fc_b = (const float*)d_in[6];
  float* outp = (float*)d_out;

  int B = in_sizes[0] / 4096;      // 16384
  int grid = (B + 31) / 32;        // 2 tiles (32 rows) per 1-wave block
  rnn_fused<<<grid, 64, 0, stream>>>(x, W_ih, W_hh, b_ih, b_hh, fc_W, fc_b, outp, B);
}

// Round 15
// 67.111 us; speedup vs baseline: 1.7661x; 1.7661x over previous
//
#include <hip/hip_runtime.h>

// Fused tanh-RNN (T=64, I=64, H=100) + tanh + linear (C=40), B=16384.
// TRANSPOSED formulation: D = A*B, A = register-resident weight fragments,
// B = data^T (x / h). W_hh/fc_W columns pre-permuted by
//   phi(32kb+8g+e) = 32kb + 16*(e>>2) + 4g + (e&3)
// so MFMA D-output regs ARE the next step's B-fragment after per-lane f16 cvt.
//
// Round-15 = round-8 champion (65.1us) + x-read LDS bank spread:
// r8's 4x ds_read_b128 starts hit only 4 of 8 16B bank offsets
// (16c+8g mod 32 in {0,8,16,24}) -> ~2x LDS phase cost. Fix: XOR byte
// bit 4 by (c&1), applied to the DMA *global source* (LDS dest stays
// linear, m173 pattern) and to the read addresses (two computed bases;
// the +128 immediate is XOR-safe since bit 4 of 128 is 0).
// All other structure bit-identical to r8 (42 MFMA/step, slab ring,
// vmcnt(16) cadence, element-wise f16 cvt packing).

typedef _Float16 half8 __attribute__((ext_vector_type(8)));
typedef float float4_t __attribute__((ext_vector_type(4)));

#define ROW_BYTES 1088                  // 1024 data + 64 pad
#define BUF_BYTES (16 * ROW_BYTES)      // 17408 per slab buffer
#define GLOAD16(gp, lp)                                                   \
  __builtin_amdgcn_global_load_lds(                                       \
      (const __attribute__((address_space(1))) void*)(gp),                \
      (__attribute__((address_space(3))) void*)(lp), 16, 0, 0)

__device__ __forceinline__ float tanh_fast(float x) {
  float e = __builtin_amdgcn_exp2f(x * 2.8853900817779268f);
  return 1.0f - 2.0f * __builtin_amdgcn_rcpf(e + 1.0f);
}

// Issue one slab: row j's bytes [slab*1024, +1024) -> buf + j*1088 (linear
// dest). Global source pre-swizzled: lane float idx = (lane*4) ^ ((j&1)<<2)
// i.e. byte (lane*16) ^ ((j&1)<<4), so LDS byte p of row j holds global
// byte p ^ ((j&1)<<4) of that row's slab window.
__device__ __forceinline__ void issue_slab(const float* src0, int slab,
                                           char* buf, int lane) {
  #pragma unroll
  for (int j = 0; j < 16; ++j) {
    int loff = (lane * 4) ^ ((j & 1) << 2);
    GLOAD16(src0 + (size_t)j * 4096 + slab * 256 + loff, buf + j * ROW_BYTES);
  }
}

__global__ __launch_bounds__(64, 1) void rnn_fused(
    const float* __restrict__ x, const float* __restrict__ W_ih,
    const float* __restrict__ W_hh, const float* __restrict__ b_ih,
    const float* __restrict__ b_hh, const float* __restrict__ fc_W,
    const float* __restrict__ fc_b, float* __restrict__ out, int B)
{
  __shared__ char xring[2 * BUF_BYTES];   // 34816 B -> 4 blocks/CU
  const int lane = threadIdx.x & 63;
  const int g = lane >> 4;   // k-group / D-row group
  const int c = lane & 15;   // batch col (B,D) == weight row (A)
  const int rowbase = blockIdx.x * 16;

  // ---- A-fragment weights, register-resident.
  half8 wih[2][7];    // W_ih[16nt+c][32kb+8g+e]
  half8 whh[4][7];    // W_hh[16nt+c][phi(32kb+8g+e)]
  float4_t bias[7];   // (b_ih+b_hh)[16nt+4g+v]

  #pragma unroll
  for (int nt = 0; nt < 7; ++nt) {
    int nb = nt * 16 + 4 * g;
    float4_t bi = {0.f, 0.f, 0.f, 0.f};
    if (nb + 3 < 100) {
      float4_t a = *(const float4_t*)(b_ih + nb);
      float4_t b = *(const float4_t*)(b_hh + nb);
      bi = a + b;
    }
    bias[nt] = bi;

    int nrow = nt * 16 + c;
    bool rv = (nrow < 100);
    #pragma unroll
    for (int kb = 0; kb < 2; ++kb) {
      float4_t f0 = {0.f,0.f,0.f,0.f}, f1 = {0.f,0.f,0.f,0.f};
      if (rv) {
        const float* p = W_ih + nrow * 64 + kb * 32 + g * 8;
        f0 = *(const float4_t*)p;
        f1 = *(const float4_t*)(p + 4);
      }
      half8 h;
      #pragma unroll
      for (int j = 0; j < 4; ++j) { h[j] = (_Float16)f0[j]; h[4 + j] = (_Float16)f1[j]; }
      wih[kb][nt] = h;
    }
    #pragma unroll
    for (int kb = 0; kb < 4; ++kb) {
      // phi: elements 0..3 -> cols 32kb+4g+0..3 ; elements 4..7 -> +16
      int clo = kb * 32 + 4 * g;
      int chi = clo + 16;
      float4_t f0 = {0.f,0.f,0.f,0.f}, f1 = {0.f,0.f,0.f,0.f};
      if (rv && clo + 3 < 100) f0 = *(const float4_t*)(W_hh + nrow * 100 + clo);
      if (rv && chi + 3 < 100) f1 = *(const float4_t*)(W_hh + nrow * 100 + chi);
      half8 h;
      #pragma unroll
      for (int j = 0; j < 4; ++j) { h[j] = (_Float16)f0[j]; h[4 + j] = (_Float16)f1[j]; }
      whh[kb][nt] = h;
    }
  }

  // ---- x slab DMA (swizzled source, linear dest)
  const float* src0 = x + (size_t)rowbase * 4096;
  issue_slab(src0, 0, xring, lane);
  issue_slab(src0, 1, xring + BUF_BYTES, lane);

  const unsigned ring_base =
      (unsigned)(uintptr_t)(__attribute__((address_space(3))) char*)xring;
  // Reader bases: LDS byte = G ^ ((c&1)<<4) where G = step-local global byte.
  // G0 = g*32 (bit4 clear) -> xg0; G0+16 -> xg1. +128 / +t4*256 / +BUF are
  // all bit4-clear adds, so immediate offset:128 and the per-step adds are
  // XOR-safe on both bases.
  const unsigned sw = (unsigned)((c & 1) << 4);
  const unsigned xg0 = ring_base + (unsigned)(c * ROW_BYTES) + ((unsigned)(g * 32) ^ sw);
  const unsigned xg1 = ring_base + (unsigned)(c * ROW_BYTES) + ((unsigned)(g * 32 + 16) ^ sw);

  float4_t acc[7];
  half8 hfrag[4];
  #pragma unroll
  for (int kb = 0; kb < 4; ++kb) hfrag[kb] = (half8)(_Float16)0.0f;  // h_0 = 0

  for (int grp = 0; grp < 16; ++grp) {
    // slab grp landed once only the 16 newer DMAs remain in flight
    asm volatile("s_waitcnt vmcnt(16)" ::: "memory");
    unsigned bofs = (unsigned)((grp & 1) * BUF_BYTES);

    #pragma unroll
    for (int t4 = 0; t4 < 4; ++t4) {
      // x fragment for step t = 4*grp + t4 (asm: invisible to waitcnt pass)
      unsigned a0 = xg0 + bofs + (unsigned)(t4 * 256);
      unsigned a1 = xg1 + bofs + (unsigned)(t4 * 256);
      float4_t s0, s1, s2, s3;
      asm volatile(
          "ds_read_b128 %0, %4 offset:0\n\t"
          "ds_read_b128 %1, %5 offset:0\n\t"
          "ds_read_b128 %2, %4 offset:128\n\t"
          "ds_read_b128 %3, %5 offset:128\n\t"
          "s_waitcnt lgkmcnt(0)"
          : "=&v"(s0), "=&v"(s1), "=&v"(s2), "=&v"(s3)
          : "v"(a0), "v"(a1) : "memory");
      __builtin_amdgcn_sched_barrier(0);

      // recurrence first (register-fed)
      #pragma unroll
      for (int nt = 0; nt < 7; ++nt)
        acc[nt] = __builtin_amdgcn_mfma_f32_16x16x32_f16(whh[0][nt], hfrag[0], bias[nt], 0, 0, 0);
      #pragma unroll
      for (int kb = 1; kb < 4; ++kb)
        #pragma unroll
        for (int nt = 0; nt < 7; ++nt)
          acc[nt] = __builtin_amdgcn_mfma_f32_16x16x32_f16(whh[kb][nt], hfrag[kb], acc[nt], 0, 0, 0);

      // input projection
      half8 xb0, xb1;
      #pragma unroll
      for (int j = 0; j < 4; ++j) {
        xb0[j] = (_Float16)s0[j]; xb0[4 + j] = (_Float16)s1[j];
        xb1[j] = (_Float16)s2[j]; xb1[4 + j] = (_Float16)s3[j];
      }
      #pragma unroll
      for (int nt = 0; nt < 7; ++nt) {
        acc[nt] = __builtin_amdgcn_mfma_f32_16x16x32_f16(wih[0][nt], xb0, acc[nt], 0, 0, 0);
        acc[nt] = __builtin_amdgcn_mfma_f32_16x16x32_f16(wih[1][nt], xb1, acc[nt], 0, 0, 0);
      }

      // h_{t+1} = tanh(preact); D regs -> next B-frag via per-lane cvt only
      #pragma unroll
      for (int nt = 0; nt < 7; ++nt)
        #pragma unroll
        for (int v = 0; v < 4; ++v)
          acc[nt][v] = tanh_fast(acc[nt][v]);

      #pragma unroll
      for (int kb = 0; kb < 4; ++kb) {
        half8 h;
        #pragma unroll
        for (int v = 0; v < 4; ++v) {
          h[v] = (_Float16)acc[2 * kb][v];
          h[4 + v] = (kb < 3) ? (_Float16)acc[2 * kb + 1][v] : (_Float16)0.0f;
        }
        hfrag[kb] = h;
      }
    }

    // refill the buffer we just finished reading (clamped tail keeps cadence)
    int sl = grp + 2; if (sl > 15) sl = 15;
    issue_slab(src0, sl, xring + (grp & 1) * BUF_BYTES, lane);
  }

  // ---- epilogue: out^T = fc_W * tanh(h_last)^T + fc_b (phi-permuted fc_W)
  #pragma unroll
  for (int nt = 0; nt < 7; ++nt)
    #pragma unroll
    for (int v = 0; v < 4; ++v)
      acc[nt][v] = tanh_fast(acc[nt][v]);
  #pragma unroll
  for (int kb = 0; kb < 4; ++kb) {
    half8 h;
    #pragma unroll
    for (int v = 0; v < 4; ++v) {
      h[v] = (_Float16)acc[2 * kb][v];
      h[4 + v] = (kb < 3) ? (_Float16)acc[2 * kb + 1][v] : (_Float16)0.0f;
    }
    hfrag[kb] = h;
  }

  half8 wfc[4][3];
  float4_t bfc[3];
  #pragma unroll
  for (int nt = 0; nt < 3; ++nt) {
    int nb = nt * 16 + 4 * g;
    float4_t bi = {0.f,0.f,0.f,0.f};
    if (nb + 3 < 40) bi = *(const float4_t*)(fc_b + nb);
    bfc[nt] = bi;

    int nrow = nt * 16 + c;
    bool rv = (nrow < 40);
    #pragma unroll
    for (int kb = 0; kb < 4; ++kb) {
      int clo = kb * 32 + 4 * g;
      int chi = clo + 16;
      float4_t f0 = {0.f,0.f,0.f,0.f}, f1 = {0.f,0.f,0.f,0.f};
      if (rv && clo + 3 < 100) f0 = *(const float4_t*)(fc_W + nrow * 100 + clo);
      if (rv && chi + 3 < 100) f1 = *(const float4_t*)(fc_W + nrow * 100 + chi);
      half8 h;
      #pragma unroll
      for (int j = 0; j < 4; ++j) { h[j] = (_Float16)f0[j]; h[4 + j] = (_Float16)f1[j]; }
      wfc[kb][nt] = h;
    }
  }

  float4_t oacc[3];
  #pragma unroll
  for (int nt = 0; nt < 3; ++nt) oacc[nt] = bfc[nt];
  #pragma unroll
  for (int kb = 0; kb < 4; ++kb)
    #pragma unroll
    for (int nt = 0; nt < 3; ++nt)
      oacc[nt] = __builtin_amdgcn_mfma_f32_16x16x32_f16(wfc[kb][nt], hfrag[kb], oacc[nt], 0, 0, 0);

  // store: lane (g,c) holds out[rowbase+c][n = 16nt+4g+v]
  #pragma unroll
  for (int nt = 0; nt < 3; ++nt)
    #pragma unroll
    for (int v = 0; v < 4; ++v) {
      int n = nt * 16 + 4 * g + v;
      if (n < 40)
        out[(size_t)(rowbase + c) * 40 + n] = oacc[nt][v];
    }
}

extern "C" void kernel_launch(void* const* d_in, const int* in_sizes, int n_in,
                              void* d_out, int out_size, void* d_ws, size_t ws_size,
                              hipStream_t stream) {
  const float* x    = (const float*)d_in[0];
  const float* W_ih = (const float*)d_in[1];
  const float* W_hh = (const float*)d_in[2];
  const float* b_ih = (const float*)d_in[3];
  const float* b_hh = (const float*)d_in[4];
  const float* fc_W = (const float*)d_in[5];
  const float* fc_b = (const float*)d_in[6];
  float* outp = (float*)d_out;

  int B = in_sizes[0] / 4096;      // 16384
  int grid = (B + 15) / 16;        // one 16-row tile per 1-wave block
  rnn_fused<<<grid, 64, 0, stream>>>(x, W_ih, W_hh, b_ih, b_hh, fc_W, fc_b, outp, B);
}

// Round 16
// 65.476 us; speedup vs baseline: 1.8102x; 1.0250x over previous
//
#include <hip/hip_runtime.h>

// Fused tanh-RNN (T=64, I=64, H=100) + tanh + linear (C=40), B=16384.
// TRANSPOSED formulation: D = A*B, A = register-resident weight fragments,
// B = data^T (x / h). W_hh/fc_W columns pre-permuted by
//   phi(32kb+8g+e) = 32kb + 16*(e>>2) + 4g + (e&3)
// so MFMA D-output regs ARE the next step's B-fragment after per-lane f16 cvt.
//
// FINAL (round-16) = round-8 champion restored bit-identical (65.1 us).
// Session finding: 12 structurally distinct variants (register prefetch,
// DMA rings, asm-invisible LDS, wave splits, slab granules, pkrtz, ladders,
// split chains, SMT) all land 65-68 us = 42 MFMA slots/SIMD/step x ~58 cyc
// solo-wave issue interval x 64 steps. 42 slots is the f16 minimum
// (K_total=164 -> 6/nt x 7 nt); >1 independent wave/SIMD is impossible
// (B/16 = 1024 tiles = 1024 SIMDs); i8/fp8 fail the 2% absmax threshold.
// Structural ceiling for this formulation.

typedef _Float16 half8 __attribute__((ext_vector_type(8)));
typedef float float4_t __attribute__((ext_vector_type(4)));

#define ROW_BYTES 1088                  // 1024 data + 64 pad
#define BUF_BYTES (16 * ROW_BYTES)      // 17408 per slab buffer
#define GLOAD16(gp, lp)                                                   \
  __builtin_amdgcn_global_load_lds(                                       \
      (const __attribute__((address_space(1))) void*)(gp),                \
      (__attribute__((address_space(3))) void*)(lp), 16, 0, 0)

__device__ __forceinline__ float tanh_fast(float x) {
  float e = __builtin_amdgcn_exp2f(x * 2.8853900817779268f);
  return 1.0f - 2.0f * __builtin_amdgcn_rcpf(e + 1.0f);
}

// Issue one slab: row j's bytes [slab*1024, slab*1024+1024) -> buf + j*1088.
// Per issue: 64 lanes x 16B = 1KB contiguous global, linear LDS dest.
__device__ __forceinline__ void issue_slab(const float* srcl, int slab, char* buf) {
  const float* s = srcl + slab * 256;
  #pragma unroll
  for (int j = 0; j < 16; ++j) {
    GLOAD16(s, buf + j * ROW_BYTES);
    s += 4096;
  }
}

__global__ __launch_bounds__(64, 1) void rnn_fused(
    const float* __restrict__ x, const float* __restrict__ W_ih,
    const float* __restrict__ W_hh, const float* __restrict__ b_ih,
    const float* __restrict__ b_hh, const float* __restrict__ fc_W,
    const float* __restrict__ fc_b, float* __restrict__ out, int B)
{
  __shared__ char xring[2 * BUF_BYTES];   // 34816 B -> 4 blocks/CU
  const int lane = threadIdx.x & 63;
  const int g = lane >> 4;   // k-group / D-row group
  const int c = lane & 15;   // batch col (B,D) == weight row (A)
  const int rowbase = blockIdx.x * 16;

  // ---- A-fragment weights, register-resident.
  half8 wih[2][7];    // W_ih[16nt+c][32kb+8g+e]
  half8 whh[4][7];    // W_hh[16nt+c][phi(32kb+8g+e)]
  float4_t bias[7];   // (b_ih+b_hh)[16nt+4g+v]

  #pragma unroll
  for (int nt = 0; nt < 7; ++nt) {
    int nb = nt * 16 + 4 * g;
    float4_t bi = {0.f, 0.f, 0.f, 0.f};
    if (nb + 3 < 100) {
      float4_t a = *(const float4_t*)(b_ih + nb);
      float4_t b = *(const float4_t*)(b_hh + nb);
      bi = a + b;
    }
    bias[nt] = bi;

    int nrow = nt * 16 + c;
    bool rv = (nrow < 100);
    #pragma unroll
    for (int kb = 0; kb < 2; ++kb) {
      float4_t f0 = {0.f,0.f,0.f,0.f}, f1 = {0.f,0.f,0.f,0.f};
      if (rv) {
        const float* p = W_ih + nrow * 64 + kb * 32 + g * 8;
        f0 = *(const float4_t*)p;
        f1 = *(const float4_t*)(p + 4);
      }
      half8 h;
      #pragma unroll
      for (int j = 0; j < 4; ++j) { h[j] = (_Float16)f0[j]; h[4 + j] = (_Float16)f1[j]; }
      wih[kb][nt] = h;
    }
    #pragma unroll
    for (int kb = 0; kb < 4; ++kb) {
      int clo = kb * 32 + 4 * g;
      int chi = clo + 16;
      float4_t f0 = {0.f,0.f,0.f,0.f}, f1 = {0.f,0.f,0.f,0.f};
      if (rv && clo + 3 < 100) f0 = *(const float4_t*)(W_hh + nrow * 100 + clo);
      if (rv && chi + 3 < 100) f1 = *(const float4_t*)(W_hh + nrow * 100 + chi);
      half8 h;
      #pragma unroll
      for (int j = 0; j < 4; ++j) { h[j] = (_Float16)f0[j]; h[4 + j] = (_Float16)f1[j]; }
      whh[kb][nt] = h;
    }
  }

  // ---- x slab DMA: lane reads 16B at (row rowbase+j, byte slab*1024 + lane*16)
  const float* srcl = x + (size_t)rowbase * 4096 + lane * 4;

  // prologue: slabs 0,1 -> 32 outstanding
  issue_slab(srcl, 0, xring);
  issue_slab(srcl, 1, xring + BUF_BYTES);

  const unsigned ring_base =
      (unsigned)(uintptr_t)(__attribute__((address_space(3))) char*)xring;
  const unsigned xa0 = ring_base + (unsigned)(c * ROW_BYTES + g * 32);

  float4_t acc[7];
  half8 hfrag[4];
  #pragma unroll
  for (int kb = 0; kb < 4; ++kb) hfrag[kb] = (half8)(_Float16)0.0f;  // h_0 = 0

  for (int grp = 0; grp < 16; ++grp) {
    // slab grp landed once only the 16 newer DMAs remain in flight
    asm volatile("s_waitcnt vmcnt(16)" ::: "memory");
    unsigned xg = xa0 + (unsigned)((grp & 1) * BUF_BYTES);

    #pragma unroll
    for (int t4 = 0; t4 < 4; ++t4) {
      // x fragment for step t = 4*grp + t4 (asm: invisible to waitcnt pass;
      // "memory" clobber keeps the end-of-group DMA issues below these reads)
      unsigned xs = xg + (unsigned)(t4 * 256);
      float4_t s0, s1, s2, s3;
      asm volatile(
          "ds_read_b128 %0, %4 offset:0\n\t"
          "ds_read_b128 %1, %4 offset:16\n\t"
          "ds_read_b128 %2, %4 offset:128\n\t"
          "ds_read_b128 %3, %4 offset:144\n\t"
          "s_waitcnt lgkmcnt(0)"
          : "=&v"(s0), "=&v"(s1), "=&v"(s2), "=&v"(s3)
          : "v"(xs) : "memory");
      __builtin_amdgcn_sched_barrier(0);

      // recurrence first (register-fed)
      #pragma unroll
      for (int nt = 0; nt < 7; ++nt)
        acc[nt] = __builtin_amdgcn_mfma_f32_16x16x32_f16(whh[0][nt], hfrag[0], bias[nt], 0, 0, 0);
      #pragma unroll
      for (int kb = 1; kb < 4; ++kb)
        #pragma unroll
        for (int nt = 0; nt < 7; ++nt)
          acc[nt] = __builtin_amdgcn_mfma_f32_16x16x32_f16(whh[kb][nt], hfrag[kb], acc[nt], 0, 0, 0);

      // input projection
      half8 xb0, xb1;
      #pragma unroll
      for (int j = 0; j < 4; ++j) {
        xb0[j] = (_Float16)s0[j]; xb0[4 + j] = (_Float16)s1[j];
        xb1[j] = (_Float16)s2[j]; xb1[4 + j] = (_Float16)s3[j];
      }
      #pragma unroll
      for (int nt = 0; nt < 7; ++nt) {
        acc[nt] = __builtin_amdgcn_mfma_f32_16x16x32_f16(wih[0][nt], xb0, acc[nt], 0, 0, 0);
        acc[nt] = __builtin_amdgcn_mfma_f32_16x16x32_f16(wih[1][nt], xb1, acc[nt], 0, 0, 0);
      }

      // h_{t+1} = tanh(preact); D regs -> next B-frag via per-lane cvt only
      #pragma unroll
      for (int nt = 0; nt < 7; ++nt)
        #pragma unroll
        for (int v = 0; v < 4; ++v)
          acc[nt][v] = tanh_fast(acc[nt][v]);

      #pragma unroll
      for (int kb = 0; kb < 4; ++kb) {
        half8 h;
        #pragma unroll
        for (int v = 0; v < 4; ++v) {
          h[v] = (_Float16)acc[2 * kb][v];
          h[4 + v] = (kb < 3) ? (_Float16)acc[2 * kb + 1][v] : (_Float16)0.0f;
        }
        hfrag[kb] = h;
      }
    }

    // issue slab grp+2 into the buffer we just finished reading (clamped
    // tail re-issues slab 15 -> keeps the vmcnt cadence constant; lgkm(0)
    // inside each step guarantees all reads of this buffer completed)
    int sl = grp + 2; if (sl > 15) sl = 15;
    issue_slab(srcl, sl, xring + (grp & 1) * BUF_BYTES);
  }

  // ---- epilogue: out^T = fc_W * tanh(h_last)^T + fc_b (phi-permuted fc_W)
  #pragma unroll
  for (int nt = 0; nt < 7; ++nt)
    #pragma unroll
    for (int v = 0; v < 4; ++v)
      acc[nt][v] = tanh_fast(acc[nt][v]);
  #pragma unroll
  for (int kb = 0; kb < 4; ++kb) {
    half8 h;
    #pragma unroll
    for (int v = 0; v < 4; ++v) {
      h[v] = (_Float16)acc[2 * kb][v];
      h[4 + v] = (kb < 3) ? (_Float16)acc[2 * kb + 1][v] : (_Float16)0.0f;
    }
    hfrag[kb] = h;
  }

  half8 wfc[4][3];
  float4_t bfc[3];
  #pragma unroll
  for (int nt = 0; nt < 3; ++nt) {
    int nb = nt * 16 + 4 * g;
    float4_t bi = {0.f,0.f,0.f,0.f};
    if (nb + 3 < 40) bi = *(const float4_t*)(fc_b + nb);
    bfc[nt] = bi;

    int nrow = nt * 16 + c;
    bool rv = (nrow < 40);
    #pragma unroll
    for (int kb = 0; kb < 4; ++kb) {
      int clo = kb * 32 + 4 * g;
      int chi = clo + 16;
      float4_t f0 = {0.f,0.f,0.f,0.f}, f1 = {0.f,0.f,0.f,0.f};
      if (rv && clo + 3 < 100) f0 = *(const float4_t*)(fc_W + nrow * 100 + clo);
      if (rv && chi + 3 < 100) f1 = *(const float4_t*)(fc_W + nrow * 100 + chi);
      half8 h;
      #pragma unroll
      for (int j = 0; j < 4; ++j) { h[j] = (_Float16)f0[j]; h[4 + j] = (_Float16)f1[j]; }
      wfc[kb][nt] = h;
    }
  }

  float4_t oacc[3];
  #pragma unroll
  for (int nt = 0; nt < 3; ++nt) oacc[nt] = bfc[nt];
  #pragma unroll
  for (int kb = 0; kb < 4; ++kb)
    #pragma unroll
    for (int nt = 0; nt < 3; ++nt)
      oacc[nt] = __builtin_amdgcn_mfma_f32_16x16x32_f16(wfc[kb][nt], hfrag[kb], oacc[nt], 0, 0, 0);

  // store: lane (g,c) holds out[rowbase+c][n = 16nt+4g+v]
  #pragma unroll
  for (int nt = 0; nt < 3; ++nt)
    #pragma unroll
    for (int v = 0; v < 4; ++v) {
      int n = nt * 16 + 4 * g + v;
      if (n < 40)
        out[(size_t)(rowbase + c) * 40 + n] = oacc[nt][v];
    }
}

extern "C" void kernel_launch(void* const* d_in, const int* in_sizes, int n_in,
                              void* d_out, int out_size, void* d_ws, size_t ws_size,
                              hipStream_t stream) {
  const float* x    = (const float*)d_in[0];
  const float* W_ih = (const float*)d_in[1];
  const float* W_hh = (const float*)d_in[2];
  const float* b_ih = (const float*)d_in[3];
  const float* b_hh = (const float*)d_in[4];
  const float* fc_W = (const float*)d_in[5];
  const float* fc_b = (const float*)d_in[6];
  float* outp = (float*)d_out;

  int B = in_sizes[0] / 4096;      // 16384
  int grid = (B + 15) / 16;        // one 16-row tile per 1-wave block
  rnn_fused<<<grid, 64, 0, stream>>>(x, W_ih, W_hh, b_ih, b_hh, fc_W, fc_b, outp, B);
}